// Round 1
// baseline (9.685 us; speedup 1.0000x reference)
//
#include <hip/hip_runtime.h>

#define HID 1024

// One wave (64 lanes) per output element j.
// Each output j needs 6 dot products of length HID:
//   rows j, j+H, j+2H of w_ih (gates r,z,n vs x)  and same rows of w_hh (vs h).
// Lane i loads float4 at element k*256 + 4*i  (k=0..3) -> fully coalesced 1KB/instr.
__global__ __launch_bounds__(256) void gru_step_kernel(
    const int*   __restrict__ inp,
    const float* __restrict__ hidden,
    const float* __restrict__ emb,
    const float* __restrict__ w_ih,
    const float* __restrict__ w_hh,
    const float* __restrict__ b_ih,
    const float* __restrict__ b_hh,
    float*       __restrict__ out)
{
    const int lane = threadIdx.x & 63;
    const int j    = (blockIdx.x * blockDim.x + threadIdx.x) >> 6;  // output index
    if (j >= HID) return;

    const int   token = inp[0];
    const int   idx   = token < 0 ? 0 : token;          // clamp; OOV masked below
    const float xmask = (token == -1) ? 0.0f : 1.0f;

    const float* __restrict__ xrow = emb + (size_t)idx * HID;

    const float* __restrict__ r0 = w_ih + (size_t)j * HID;               // i_r row
    const float* __restrict__ r1 = r0 + (size_t)HID * HID;               // i_z row
    const float* __restrict__ r2 = r1 + (size_t)HID * HID;               // i_n row
    const float* __restrict__ r3 = w_hh + (size_t)j * HID;               // h_r row
    const float* __restrict__ r4 = r3 + (size_t)HID * HID;               // h_z row
    const float* __restrict__ r5 = r4 + (size_t)HID * HID;               // h_n row

    float a0 = 0.f, a1 = 0.f, a2 = 0.f, a3 = 0.f, a4 = 0.f, a5 = 0.f;

    #pragma unroll
    for (int k = 0; k < 4; ++k) {
        const int off = k * 256 + lane * 4;
        const float4 xv = *(const float4*)(xrow   + off);
        const float4 hv = *(const float4*)(hidden + off);
        float4 w;
        w = *(const float4*)(r0 + off);
        a0 += w.x * xv.x + w.y * xv.y + w.z * xv.z + w.w * xv.w;
        w = *(const float4*)(r1 + off);
        a1 += w.x * xv.x + w.y * xv.y + w.z * xv.z + w.w * xv.w;
        w = *(const float4*)(r2 + off);
        a2 += w.x * xv.x + w.y * xv.y + w.z * xv.z + w.w * xv.w;
        w = *(const float4*)(r3 + off);
        a3 += w.x * hv.x + w.y * hv.y + w.z * hv.z + w.w * hv.w;
        w = *(const float4*)(r4 + off);
        a4 += w.x * hv.x + w.y * hv.y + w.z * hv.z + w.w * hv.w;
        w = *(const float4*)(r5 + off);
        a5 += w.x * hv.x + w.y * hv.y + w.z * hv.z + w.w * hv.w;
    }

    // Butterfly reduction across the 64-lane wave.
    #pragma unroll
    for (int s = 32; s > 0; s >>= 1) {
        a0 += __shfl_xor(a0, s);
        a1 += __shfl_xor(a1, s);
        a2 += __shfl_xor(a2, s);
        a3 += __shfl_xor(a3, s);
        a4 += __shfl_xor(a4, s);
        a5 += __shfl_xor(a5, s);
    }

    if (lane == 0) {
        const float i_r = xmask * a0 + b_ih[j];
        const float i_z = xmask * a1 + b_ih[j + HID];
        const float i_n = xmask * a2 + b_ih[j + 2 * HID];
        const float h_r = a3 + b_hh[j];
        const float h_z = a4 + b_hh[j + HID];
        const float h_n = a5 + b_hh[j + 2 * HID];

        const float r = 1.0f / (1.0f + expf(-(i_r + h_r)));
        const float z = 1.0f / (1.0f + expf(-(i_z + h_z)));
        const float n = tanhf(i_n + r * h_n);
        const float h = hidden[j];
        const float hn = (1.0f - z) * n + z * h;

        out[j]       = hn;   // tuple element 0
        out[j + HID] = hn;   // tuple element 1 (same tensor)
    }
}

extern "C" void kernel_launch(void* const* d_in, const int* in_sizes, int n_in,
                              void* d_out, int out_size, void* d_ws, size_t ws_size,
                              hipStream_t stream) {
    const int*   inp    = (const int*)  d_in[0];
    const float* hidden = (const float*)d_in[1];
    const float* emb    = (const float*)d_in[2];
    const float* w_ih   = (const float*)d_in[3];
    const float* w_hh   = (const float*)d_in[4];
    const float* b_ih   = (const float*)d_in[5];
    const float* b_hh   = (const float*)d_in[6];
    float* out = (float*)d_out;

    // 1024 output elements, one 64-lane wave each -> 1024 waves = 256 blocks x 256 thr
    gru_step_kernel<<<dim3(256), dim3(256), 0, stream>>>(
        inp, hidden, emb, w_ih, w_hh, b_ih, b_hh, out);
}

// Round 6
// 9.593 us; speedup vs baseline: 1.0096x; 1.0096x over previous
//
#include <hip/hip_runtime.h>

#define HID 1024

// One block (256 threads = 4 waves) per output element j.
// Thread t owns elements [4t, 4t+4) of the 1024-long dot products:
//   loads one float4 from each of the 6 weight rows (j, j+H, j+2H of w_ih/w_hh),
//   one float4 of x (emb row) and one of h (hidden).
// Per-wave butterfly reduce -> 4 partials per gate in LDS -> thread 0 combines.
__global__ __launch_bounds__(256) void gru_step_kernel(
    const int*   __restrict__ inp,
    const float* __restrict__ hidden,
    const float* __restrict__ emb,
    const float* __restrict__ w_ih,
    const float* __restrict__ w_hh,
    const float* __restrict__ b_ih,
    const float* __restrict__ b_hh,
    float*       __restrict__ out)
{
    __shared__ float part[4][6];

    const int tid  = threadIdx.x;
    const int lane = tid & 63;
    const int wv   = tid >> 6;
    const int j    = blockIdx.x;          // output index, grid = HID blocks
    const int off  = tid * 4;             // element offset in [0, 1024)

    const int   token = inp[0];
    const int   idx   = token < 0 ? 0 : token;           // clamp; OOV masked below
    const float xmask = (token == -1) ? 0.0f : 1.0f;

    const float4 xv = *(const float4*)(emb + (size_t)idx * HID + off);
    const float4 hv = *(const float4*)(hidden + off);

    const float* __restrict__ r0 = w_ih + (size_t)j * HID + off;          // i_r
    const float* __restrict__ r1 = r0 + (size_t)HID * HID;                // i_z
    const float* __restrict__ r2 = r1 + (size_t)HID * HID;                // i_n
    const float* __restrict__ r3 = w_hh + (size_t)j * HID + off;          // h_r
    const float* __restrict__ r4 = r3 + (size_t)HID * HID;                // h_z
    const float* __restrict__ r5 = r4 + (size_t)HID * HID;                // h_n

    const float4 w0 = *(const float4*)r0;
    const float4 w1 = *(const float4*)r1;
    const float4 w2 = *(const float4*)r2;
    const float4 w3 = *(const float4*)r3;
    const float4 w4 = *(const float4*)r4;
    const float4 w5 = *(const float4*)r5;

    float a0 = w0.x * xv.x + w0.y * xv.y + w0.z * xv.z + w0.w * xv.w;
    float a1 = w1.x * xv.x + w1.y * xv.y + w1.z * xv.z + w1.w * xv.w;
    float a2 = w2.x * xv.x + w2.y * xv.y + w2.z * xv.z + w2.w * xv.w;
    float a3 = w3.x * hv.x + w3.y * hv.y + w3.z * hv.z + w3.w * hv.w;
    float a4 = w4.x * hv.x + w4.y * hv.y + w4.z * hv.z + w4.w * hv.w;
    float a5 = w5.x * hv.x + w5.y * hv.y + w5.z * hv.z + w5.w * hv.w;

    // Butterfly reduction across the 64-lane wave.
    #pragma unroll
    for (int s = 32; s > 0; s >>= 1) {
        a0 += __shfl_xor(a0, s);
        a1 += __shfl_xor(a1, s);
        a2 += __shfl_xor(a2, s);
        a3 += __shfl_xor(a3, s);
        a4 += __shfl_xor(a4, s);
        a5 += __shfl_xor(a5, s);
    }

    if (lane == 0) {
        part[wv][0] = a0; part[wv][1] = a1; part[wv][2] = a2;
        part[wv][3] = a3; part[wv][4] = a4; part[wv][5] = a5;
    }
    __syncthreads();

    if (tid == 0) {
        const float s0 = part[0][0] + part[1][0] + part[2][0] + part[3][0];
        const float s1 = part[0][1] + part[1][1] + part[2][1] + part[3][1];
        const float s2 = part[0][2] + part[1][2] + part[2][2] + part[3][2];
        const float s3 = part[0][3] + part[1][3] + part[2][3] + part[3][3];
        const float s4 = part[0][4] + part[1][4] + part[2][4] + part[3][4];
        const float s5 = part[0][5] + part[1][5] + part[2][5] + part[3][5];

        const float i_r = xmask * s0 + b_ih[j];
        const float i_z = xmask * s1 + b_ih[j + HID];
        const float i_n = xmask * s2 + b_ih[j + 2 * HID];
        const float h_r = s3 + b_hh[j];
        const float h_z = s4 + b_hh[j + HID];
        const float h_n = s5 + b_hh[j + 2 * HID];

        const float r = 1.0f / (1.0f + expf(-(i_r + h_r)));
        const float z = 1.0f / (1.0f + expf(-(i_z + h_z)));
        const float n = tanhf(i_n + r * h_n);
        const float h = hidden[j];
        const float hn = (1.0f - z) * n + z * h;

        out[j]       = hn;   // tuple element 0
        out[j + HID] = hn;   // tuple element 1 (same tensor)
    }
}

extern "C" void kernel_launch(void* const* d_in, const int* in_sizes, int n_in,
                              void* d_out, int out_size, void* d_ws, size_t ws_size,
                              hipStream_t stream) {
    const int*   inp    = (const int*)  d_in[0];
    const float* hidden = (const float*)d_in[1];
    const float* emb    = (const float*)d_in[2];
    const float* w_ih   = (const float*)d_in[3];
    const float* w_hh   = (const float*)d_in[4];
    const float* b_ih   = (const float*)d_in[5];
    const float* b_hh   = (const float*)d_in[6];
    float* out = (float*)d_out;

    gru_step_kernel<<<dim3(HID), dim3(256), 0, stream>>>(
        inp, hidden, emb, w_ih, w_hh, b_ih, b_hh, out);
}